// Round 11
// baseline (247.630 us; speedup 1.0000x reference)
//
#include <hip/hip_runtime.h>
#include <math.h>

#define IN_F   256
#define OUT_F  128
#define HEADS  4
#define HD     (HEADS * OUT_F)   // 512
#define K2     1024              // stacked contraction: 4 heads x 256
#define NEG    0.2f
#define CAP    64                // per-node in-edge capacity (mean deg 16)

typedef __attribute__((ext_vector_type(8))) short short8;   // 8 bf16 = 4 VGPRs
typedef __attribute__((ext_vector_type(4))) float f32x4;
typedef __attribute__((ext_vector_type(2))) float f32x2;

typedef __attribute__((address_space(1))) const void* gp_t;
typedef __attribute__((address_space(3))) void* lp_t;

static __device__ __forceinline__ ushort f2bf(float f) {
    union { float f; unsigned u; } v; v.f = f;
    unsigned r = (v.u + 0x7FFFu + ((v.u >> 16) & 1u)) >> 16;   // RNE
    return (ushort)r;
}
static __device__ __forceinline__ float bflo(unsigned u) {
    union { unsigned u; float f; } v; v.u = u << 16; return v.f;
}
static __device__ __forceinline__ float bfhi(unsigned u) {
    union { unsigned u; float f; } v; v.u = u & 0xFFFF0000u; return v.f;
}

// packed fp32 FMA: D = A*B + D (per 32-bit half)
#define PKFMA(D, A, B) asm("v_pk_fma_f32 %0, %1, %2, %0" : "+v"(D) : "v"(A), "v"(B))

// ---------------- prep1: WT2 cvt + va + cursor zero (role by blockIdx) ----------------
__global__ __launch_bounds__(256) void prep1(const float* __restrict__ W,
                                             const float* __restrict__ att_src,
                                             const float* __restrict__ att_dst,
                                             ushort* __restrict__ WT2,
                                             float* __restrict__ va_s,
                                             float* __restrict__ va_d,
                                             int* __restrict__ cursor,
                                             int n_nodes) {
    const int b = blockIdx.x;
    const int tid = threadIdx.x;
    if (b < 512) {
        int idx = b * 256 + tid;               // 128*1024
        int cout = idx >> 10, kk = idx & 1023;
        int h = kk >> 8, c = kk & 255;
        WT2[idx] = f2bf(W[(size_t)c * HD + h * OUT_F + cout]);
    } else if (b < 768) {
        const int lane = tid & 63;
        const int p = (b - 512) * 4 + (tid >> 6);   // 0..1023 = h*256 + k
        const int h = p >> 8;
        const int k = p & 255;
        const float* wr = W + (size_t)k * HD + h * OUT_F;
        float w0 = wr[lane], w1 = wr[lane + 64];
        float s0 = att_src[h * OUT_F + lane], s1 = att_src[h * OUT_F + lane + 64];
        float d0 = att_dst[h * OUT_F + lane], d1 = att_dst[h * OUT_F + lane + 64];
        float ss = w0 * s0 + w1 * s1;
        float sd = w0 * d0 + w1 * d1;
#pragma unroll
        for (int off = 32; off > 0; off >>= 1) {
            ss += __shfl_xor(ss, off, 64);
            sd += __shfl_xor(sd, off, 64);
        }
        if (lane == 0) { va_s[p] = ss; va_d[p] = sd; }
    } else {
        int i = (b - 768) * 256 + tid;
        if (i < n_nodes) cursor[i] = 0;
    }
}

// ---------------- prep2: build_table + fused_x (role by blockIdx) ----------------
__global__ __launch_bounds__(256) void prep2(const float* __restrict__ X,
                                             const float* __restrict__ va_s,
                                             const float* __restrict__ va_d,
                                             const int* __restrict__ src,
                                             const int* __restrict__ dst,
                                             ushort* __restrict__ Xb,
                                             float* __restrict__ a_s,
                                             float* __restrict__ a_d,
                                             int* __restrict__ cursor,
                                             int* __restrict__ table,
                                             int n_nodes, int n_edges, int nebk) {
    const int b = blockIdx.x;
    const int tid = threadIdx.x;
    if (b < nebk) {
        int e = b * 256 + tid;
        if (e < n_edges) {
            int d = dst[e];
            int r = atomicAdd(&cursor[d], 1);
            if (r < CAP) table[(size_t)d * CAP + r] = src[e];
        }
        return;
    }
    const int lane = tid & 63;
    const int node = (b - nebk) * 4 + (tid >> 6);
    if (node >= n_nodes) return;
    float4 v = *(const float4*)(X + (size_t)node * IN_F + lane * 4);
    ushort4 o; o.x = f2bf(v.x); o.y = f2bf(v.y); o.z = f2bf(v.z); o.w = f2bf(v.w);
    *(ushort4*)(Xb + (size_t)node * IN_F + lane * 4) = o;

    float ps[HEADS], pd[HEADS];
#pragma unroll
    for (int hd = 0; hd < HEADS; ++hd) {
        float4 s4 = *(const float4*)(va_s + hd * IN_F + lane * 4);
        float4 d4 = *(const float4*)(va_d + hd * IN_F + lane * 4);
        ps[hd] = v.x * s4.x + v.y * s4.y + v.z * s4.z + v.w * s4.w;
        pd[hd] = v.x * d4.x + v.y * d4.y + v.z * d4.z + v.w * d4.w;
    }
#pragma unroll
    for (int off = 32; off > 0; off >>= 1) {
#pragma unroll
        for (int hd = 0; hd < HEADS; ++hd) {
            ps[hd] += __shfl_xor(ps[hd], off, 64);
            pd[hd] += __shfl_xor(pd[hd], off, 64);
        }
    }
    if (lane == 0) {
        float4 s4 = make_float4(ps[0], ps[1], ps[2], ps[3]);
        float4 d4 = make_float4(pd[0], pd[1], pd[2], pd[3]);
        *(float4*)(a_s + node * 4) = s4;
        *(float4*)(a_d + node * 4) = d4;
    }
}

// --------- fused softmax + X-space aggregation: wave per node (R5-proven) ---------
// LDS-DMA gathers with per-lane addresses (1 instr = 2 edge rows), 8-edge tiles
// double-buffered with counted vmcnt(4), packed f32x2 FMA, no barriers.
#define EDGE(E8)                                                            \
    {                                                                       \
        uint2 uu = *(const uint2*)(cons + (E8) * 512);                      \
        float4 wA = *(const float4*)(wp + (E8) * 8);                        \
        float4 wB = *(const float4*)(wp + (E8) * 8 + 4);                    \
        f32x2 f01 = {bflo(uu.x), bfhi(uu.x)};                               \
        f32x2 f23 = {bflo(uu.y), bfhi(uu.y)};                               \
        f32x2 w0p = {wA.x, wA.y}, w1p = {wA.z, wA.w};                       \
        f32x2 w2p = {wB.x, wB.y}, w3p = {wB.z, wB.w};                       \
        PKFMA(a01[0], f01, w0p); PKFMA(a23[0], f23, w0p);                   \
        PKFMA(a01[1], f01, w1p); PKFMA(a23[1], f23, w1p);                   \
        PKFMA(a01[2], f01, w2p); PKFMA(a23[2], f23, w2p);                   \
        PKFMA(a01[3], f01, w3p); PKFMA(a23[3], f23, w3p);                   \
    }

#define ISSUE(EB, DST)                                                      \
    {                                                                       \
        asm volatile("s_waitcnt lgkmcnt(0)" ::: "memory");                  \
        int s0_ = __shfl(sreg, (EB) + 0, 64);                               \
        int s1_ = __shfl(sreg, (EB) + 1, 64);                               \
        int s2_ = __shfl(sreg, (EB) + 2, 64);                               \
        int s3_ = __shfl(sreg, (EB) + 3, 64);                               \
        int s4_ = __shfl(sreg, (EB) + 4, 64);                               \
        int s5_ = __shfl(sreg, (EB) + 5, 64);                               \
        int s6_ = __shfl(sreg, (EB) + 6, 64);                               \
        int s7_ = __shfl(sreg, (EB) + 7, 64);                               \
        int sa_ = (lane & 32) ? s1_ : s0_;                                  \
        int sb_ = (lane & 32) ? s3_ : s2_;                                  \
        int sc_ = (lane & 32) ? s5_ : s4_;                                  \
        int sd_ = (lane & 32) ? s7_ : s6_;                                  \
        __builtin_amdgcn_global_load_lds((gp_t)(xb16 + (size_t)sa_ * 256),  \
                                         (lp_t)((DST) + 0 * 1024), 16, 0, 0);\
        __builtin_amdgcn_global_load_lds((gp_t)(xb16 + (size_t)sb_ * 256),  \
                                         (lp_t)((DST) + 1 * 1024), 16, 0, 0);\
        __builtin_amdgcn_global_load_lds((gp_t)(xb16 + (size_t)sc_ * 256),  \
                                         (lp_t)((DST) + 2 * 1024), 16, 0, 0);\
        __builtin_amdgcn_global_load_lds((gp_t)(xb16 + (size_t)sd_ * 256),  \
                                         (lp_t)((DST) + 3 * 1024), 16, 0, 0);\
    }

__global__ __launch_bounds__(256) void gat_agg(const ushort* __restrict__ Xb,
                                               const float* __restrict__ a_s,
                                               const float* __restrict__ a_d,
                                               const int* __restrict__ cursor,
                                               const int* __restrict__ table,
                                               ushort* __restrict__ Zb,
                                               int n_nodes) {
    __shared__ ushort xst[4][2][8][256];        // 4 waves x 2 bufs x 8 edges = 32 KB
    __shared__ float wse[4][CAP][8];            // {w,w} per head per edge     =  8 KB
    const int lane = threadIdx.x & 63;
    const int wid  = threadIdx.x >> 6;
    const int n = blockIdx.x * 4 + wid;
    if (n >= n_nodes) return;                   // no barriers in this kernel
    int deg = cursor[n]; if (deg > CAP) deg = CAP;
    const int* row = table + (size_t)n * CAP;
    const bool act = lane < deg;
    int sreg = act ? row[lane] : n;             // lane e holds src[e] (self if inactive)

    const ushort* xb16 = Xb + (lane & 31) * 8;  // per-lane 16B chunk base
    const uint2* xb2 = (const uint2*)Xb;
    uint2 uself = xb2[(size_t)n * 64 + lane];   // self row (registers)

    char* xb0 = (char*)&xst[wid][0][0][0];
    char* xb1 = (char*)&xst[wid][1][0][0];

    const int ntiles = (deg + 7) >> 3;
    if (ntiles > 0) ISSUE(0, xb0);              // tile 0 in flight under softmax

    // ---- softmax over self + in-edges (lane e owns edge e) ----
    const float4 ad4 = *(const float4*)(a_d + n * 4);
    const float4 as4 = *(const float4*)(a_s + n * 4);
    const float ad[4] = {ad4.x, ad4.y, ad4.z, ad4.w};
    float aself[4];
    {
        const float asn[4] = {as4.x, as4.y, as4.z, as4.w};
#pragma unroll
        for (int hd = 0; hd < 4; ++hd) {
            float al0 = asn[hd] + ad[hd];
            aself[hd] = al0 > 0.f ? al0 : NEG * al0;
        }
    }
    float al[4];
    {
        float4 av = *(const float4*)(a_s + (size_t)sreg * 4);
        const float as_[4] = {av.x, av.y, av.z, av.w};
#pragma unroll
        for (int hd = 0; hd < 4; ++hd) {
            float a = as_[hd] + ad[hd];
            a = a > 0.f ? a : NEG * a;
            al[hd] = act ? a : -1e30f;
        }
    }
    float m[4];
#pragma unroll
    for (int hd = 0; hd < 4; ++hd) m[hd] = al[hd];
#pragma unroll
    for (int off = 32; off > 0; off >>= 1)
#pragma unroll
        for (int hd = 0; hd < 4; ++hd)
            m[hd] = fmaxf(m[hd], __shfl_xor(m[hd], off, 64));
#pragma unroll
    for (int hd = 0; hd < 4; ++hd) m[hd] = fmaxf(m[hd], aself[hd]);

    float w[4], den[4];
#pragma unroll
    for (int hd = 0; hd < 4; ++hd) {
        w[hd] = act ? __expf(al[hd] - m[hd]) : 0.f;
        den[hd] = w[hd];
    }
#pragma unroll
    for (int off = 32; off > 0; off >>= 1)
#pragma unroll
        for (int hd = 0; hd < 4; ++hd)
            den[hd] += __shfl_xor(den[hd], off, 64);

    float es[4], rdv[4];
#pragma unroll
    for (int hd = 0; hd < 4; ++hd) {
        es[hd] = __expf(aself[hd] - m[hd]);
        rdv[hd] = 1.f / (den[hd] + es[hd]);
    }

    // publish duplicated weights {w,w} (wave-private; DS ops in-order per wave)
    *(float4*)&wse[wid][lane][0] = make_float4(w[0], w[0], w[1], w[1]);
    *(float4*)&wse[wid][lane][4] = make_float4(w[2], w[2], w[3], w[3]);

    // ---- aggregation: lane owns channels 4*lane..+3, all 4 heads, packed f32x2 ----
    f32x2 a01[4], a23[4];
    {
        f32x2 s01 = {bflo(uself.x), bfhi(uself.x)};
        f32x2 s23 = {bflo(uself.y), bfhi(uself.y)};
#pragma unroll
        for (int hd = 0; hd < 4; ++hd) {
            f32x2 eh = {es[hd], es[hd]};
            a01[hd] = s01 * eh;
            a23[hd] = s23 * eh;
        }
    }
#pragma unroll 1
    for (int t = 0; t < ntiles; ++t) {
        if (t + 1 < ntiles) {
            ISSUE((t + 1) * 8, ((t + 1) & 1) ? xb1 : xb0);
            asm volatile("s_waitcnt vmcnt(4)" ::: "memory");
        } else {
            asm volatile("s_waitcnt vmcnt(0)" ::: "memory");
        }
        const char* cons = ((t & 1) ? xb1 : xb0) + lane * 8;
        const float* wp = &wse[wid][t * 8][0];
        EDGE(0); EDGE(1); EDGE(2); EDGE(3);
        EDGE(4); EDGE(5); EDGE(6); EDGE(7);
    }

    ushort* zr = Zb + (size_t)n * K2;
#pragma unroll
    for (int hd = 0; hd < 4; ++hd) {
        f32x2 r2 = {rdv[hd], rdv[hd]};
        f32x2 z01 = a01[hd] * r2;
        f32x2 z23 = a23[hd] * r2;
        ushort4 z;
        z.x = f2bf(z01.x); z.y = f2bf(z01.y);
        z.z = f2bf(z23.x); z.w = f2bf(z23.y);
        *(ushort4*)(zr + hd * 256 + lane * 4) = z;
    }
}

// ---------------- gemm2: ZERO-LDS direct-load MFMA GEMM ----------------
// out[32x128 per block] = tanh(0.25 * Zb @ WT2^T + bias), K=1024.
// Both operands load global->register (B is L2-resident 256KB; A is L2-hot Zb).
// Fragment map (verified): lane=l15+16*quad holds A[l15][quad*8+j], B[quad*8+j][l15].
// Per row the 4 quads read contiguous 64B -> clean coalescing. Register
// double-buffer (even/odd named vars, no arrays), no LDS, no barriers.
#define LOADT(AV, B0V, B1V, B2V, B3V, KO)                                   \
    {                                                                       \
        AV  = *(const short8*)(pA  + (KO));                                 \
        B0V = *(const short8*)(pB0 + (KO));                                 \
        B1V = *(const short8*)(pB1 + (KO));                                 \
        B2V = *(const short8*)(pB2 + (KO));                                 \
        B3V = *(const short8*)(pB3 + (KO));                                 \
    }
#define MFMAT(AV, B0V, B1V, B2V, B3V)                                       \
    {                                                                       \
        acc0 = __builtin_amdgcn_mfma_f32_16x16x32_bf16(AV, B0V, acc0, 0, 0, 0); \
        acc1 = __builtin_amdgcn_mfma_f32_16x16x32_bf16(AV, B1V, acc1, 0, 0, 0); \
        acc2 = __builtin_amdgcn_mfma_f32_16x16x32_bf16(AV, B2V, acc2, 0, 0, 0); \
        acc3 = __builtin_amdgcn_mfma_f32_16x16x32_bf16(AV, B3V, acc3, 0, 0, 0); \
    }

__global__ __launch_bounds__(256) void gemm2(const ushort* __restrict__ Zb,
                                             const ushort* __restrict__ WT2,
                                             const float* __restrict__ bias,
                                             float* __restrict__ out,
                                             int n_nodes) {
    const int tid = threadIdx.x;
    const int wave = tid >> 6, lane = tid & 63;
    const int m0 = blockIdx.x * 32;
    const int wm = (wave & 1) * 16, wn = (wave >> 1) * 64;
    const int l15 = lane & 15, quad = lane >> 4;

    const ushort* pA  = Zb  + (size_t)(m0 + wm + l15) * K2 + quad * 8;
    const ushort* pB0 = WT2 + (size_t)(wn +  0 + l15) * K2 + quad * 8;
    const ushort* pB1 = WT2 + (size_t)(wn + 16 + l15) * K2 + quad * 8;
    const ushort* pB2 = WT2 + (size_t)(wn + 32 + l15) * K2 + quad * 8;
    const ushort* pB3 = WT2 + (size_t)(wn + 48 + l15) * K2 + quad * 8;

    f32x4 acc0 = {0.f, 0.f, 0.f, 0.f};
    f32x4 acc1 = {0.f, 0.f, 0.f, 0.f};
    f32x4 acc2 = {0.f, 0.f, 0.f, 0.f};
    f32x4 acc3 = {0.f, 0.f, 0.f, 0.f};

    short8 aE, b0E, b1E, b2E, b3E;              // even k-step regs
    short8 aO, b0O, b1O, b2O, b3O;              // odd  k-step regs
    LOADT(aE, b0E, b1E, b2E, b3E, 0);
#pragma unroll 1
    for (int k0 = 0; k0 < K2; k0 += 64) {
        LOADT(aO, b0O, b1O, b2O, b3O, k0 + 32);            // prefetch odd
        MFMAT(aE, b0E, b1E, b2E, b3E);                     // consume even
        if (k0 + 64 < K2) LOADT(aE, b0E, b1E, b2E, b3E, k0 + 64);  // prefetch even
        MFMAT(aO, b0O, b1O, b2O, b3O);                     // consume odd
    }

    float bcol0 = bias[wn +  0 + l15];
    float bcol1 = bias[wn + 16 + l15];
    float bcol2 = bias[wn + 32 + l15];
    float bcol3 = bias[wn + 48 + l15];

    int gmb = m0 + wm + quad * 4;
#pragma unroll
    for (int reg = 0; reg < 4; ++reg) {
        int gm = gmb + reg;
        if (gm < n_nodes) {
            float* orow = out + (size_t)gm * OUT_F + wn;
            orow[ 0 + l15] = tanhf(0.25f * acc0[reg] + bcol0);
            orow[16 + l15] = tanhf(0.25f * acc1[reg] + bcol1);
            orow[32 + l15] = tanhf(0.25f * acc2[reg] + bcol2);
            orow[48 + l15] = tanhf(0.25f * acc3[reg] + bcol3);
        }
    }
}

extern "C" void kernel_launch(void* const* d_in, const int* in_sizes, int n_in,
                              void* d_out, int out_size, void* d_ws, size_t ws_size,
                              hipStream_t stream) {
    const float* x       = (const float*)d_in[0];
    const int*   ei      = (const int*)d_in[1];
    const float* W       = (const float*)d_in[2];
    const float* att_src = (const float*)d_in[3];
    const float* att_dst = (const float*)d_in[4];
    const float* bias    = (const float*)d_in[5];
    float* out = (float*)d_out;

    const int n_nodes = in_sizes[0] / IN_F;     // 30000
    const int n_edges = in_sizes[1] / 2;        // 480000
    const int* src = ei;
    const int* dst = ei + n_edges;

    char* ws = (char*)d_ws;
    size_t off = 0;
    auto alloc = [&](size_t bytes) -> void* {
        void* p = ws + off;
        off = (off + bytes + 255) & ~(size_t)255;
        return p;
    };
    ushort* Xb     = (ushort*)alloc((size_t)n_nodes * IN_F * sizeof(ushort));   // 15.4 MB
    ushort* Zb     = (ushort*)alloc((size_t)n_nodes * K2 * sizeof(ushort));     // 61.4 MB
    ushort* WT2    = (ushort*)alloc((size_t)OUT_F * K2 * sizeof(ushort));       // 0.26 MB (also pads Zb tail over-read)
    float*  va_s   = (float*)alloc((size_t)HEADS * IN_F * sizeof(float));
    float*  va_d   = (float*)alloc((size_t)HEADS * IN_F * sizeof(float));
    float*  a_s    = (float*)alloc((size_t)n_nodes * HEADS * sizeof(float));
    float*  a_d    = (float*)alloc((size_t)n_nodes * HEADS * sizeof(float));
    int*    cursor = (int*)alloc((size_t)n_nodes * sizeof(int));
    int*    table  = (int*)alloc((size_t)n_nodes * CAP * sizeof(int));          // 7.7 MB
    (void)ws_size; (void)n_in; (void)out_size;

    const int czb  = (n_nodes + 255) / 256;     // 118
    const int nebk = (n_edges + 255) / 256;     // 1875

    prep1<<<768 + czb, 256, 0, stream>>>(W, att_src, att_dst, WT2, va_s, va_d,
                                         cursor, n_nodes);
    prep2<<<nebk + (n_nodes + 3) / 4, 256, 0, stream>>>(x, va_s, va_d, src, dst,
                                                        Xb, a_s, a_d, cursor, table,
                                                        n_nodes, n_edges, nebk);
    gat_agg<<<(n_nodes + 3) / 4, 256, 0, stream>>>(Xb, a_s, a_d, cursor, table,
                                                   Zb, n_nodes);
    gemm2<<<(n_nodes + 31) / 32, 256, 0, stream>>>(Zb, WT2, bias, out, n_nodes);
}

// Round 12
// 197.036 us; speedup vs baseline: 1.2568x; 1.2568x over previous
//
#include <hip/hip_runtime.h>
#include <math.h>

#define IN_F   256
#define OUT_F  128
#define HEADS  4
#define HD     (HEADS * OUT_F)   // 512
#define K2     1024              // stacked contraction: 4 heads x 256
#define NEG    0.2f
#define CAP    64                // per-node in-edge capacity (mean deg 16)

typedef __attribute__((ext_vector_type(8))) short short8;   // 8 bf16 = 4 VGPRs
typedef __attribute__((ext_vector_type(4))) float f32x4;
typedef __attribute__((ext_vector_type(2))) float f32x2;

typedef __attribute__((address_space(1))) const void* gp_t;
typedef __attribute__((address_space(3))) void* lp_t;

static __device__ __forceinline__ ushort f2bf(float f) {
    union { float f; unsigned u; } v; v.f = f;
    unsigned r = (v.u + 0x7FFFu + ((v.u >> 16) & 1u)) >> 16;   // RNE
    return (ushort)r;
}
static __device__ __forceinline__ float bflo(unsigned u) {
    union { unsigned u; float f; } v; v.u = u << 16; return v.f;
}
static __device__ __forceinline__ float bfhi(unsigned u) {
    union { unsigned u; float f; } v; v.u = u & 0xFFFF0000u; return v.f;
}

// packed fp32 FMA: D = A*B + D (per 32-bit half)
#define PKFMA(D, A, B) asm("v_pk_fma_f32 %0, %1, %2, %0" : "+v"(D) : "v"(A), "v"(B))

// ---------------- prep1: WT2 cvt + va + cursor zero (role by blockIdx) ----------------
__global__ __launch_bounds__(256) void prep1(const float* __restrict__ W,
                                             const float* __restrict__ att_src,
                                             const float* __restrict__ att_dst,
                                             ushort* __restrict__ WT2,
                                             float* __restrict__ va_s,
                                             float* __restrict__ va_d,
                                             int* __restrict__ cursor,
                                             int n_nodes) {
    const int b = blockIdx.x;
    const int tid = threadIdx.x;
    if (b < 512) {
        int idx = b * 256 + tid;               // 128*1024
        int cout = idx >> 10, kk = idx & 1023;
        int h = kk >> 8, c = kk & 255;
        WT2[idx] = f2bf(W[(size_t)c * HD + h * OUT_F + cout]);
    } else if (b < 768) {
        const int lane = tid & 63;
        const int p = (b - 512) * 4 + (tid >> 6);   // 0..1023 = h*256 + k
        const int h = p >> 8;
        const int k = p & 255;
        const float* wr = W + (size_t)k * HD + h * OUT_F;
        float w0 = wr[lane], w1 = wr[lane + 64];
        float s0 = att_src[h * OUT_F + lane], s1 = att_src[h * OUT_F + lane + 64];
        float d0 = att_dst[h * OUT_F + lane], d1 = att_dst[h * OUT_F + lane + 64];
        float ss = w0 * s0 + w1 * s1;
        float sd = w0 * d0 + w1 * d1;
#pragma unroll
        for (int off = 32; off > 0; off >>= 1) {
            ss += __shfl_xor(ss, off, 64);
            sd += __shfl_xor(sd, off, 64);
        }
        if (lane == 0) { va_s[p] = ss; va_d[p] = sd; }
    } else {
        int i = (b - 768) * 256 + tid;
        if (i < n_nodes) cursor[i] = 0;
    }
}

// ---------------- prep2: build_table + fused_x (role by blockIdx) ----------------
__global__ __launch_bounds__(256) void prep2(const float* __restrict__ X,
                                             const float* __restrict__ va_s,
                                             const float* __restrict__ va_d,
                                             const int* __restrict__ src,
                                             const int* __restrict__ dst,
                                             ushort* __restrict__ Xb,
                                             float* __restrict__ a_s,
                                             float* __restrict__ a_d,
                                             int* __restrict__ cursor,
                                             int* __restrict__ table,
                                             int n_nodes, int n_edges, int nebk) {
    const int b = blockIdx.x;
    const int tid = threadIdx.x;
    if (b < nebk) {
        int e = b * 256 + tid;
        if (e < n_edges) {
            int d = dst[e];
            int r = atomicAdd(&cursor[d], 1);
            if (r < CAP) table[(size_t)d * CAP + r] = src[e];
        }
        return;
    }
    const int lane = tid & 63;
    const int node = (b - nebk) * 4 + (tid >> 6);
    if (node >= n_nodes) return;
    float4 v = *(const float4*)(X + (size_t)node * IN_F + lane * 4);
    ushort4 o; o.x = f2bf(v.x); o.y = f2bf(v.y); o.z = f2bf(v.z); o.w = f2bf(v.w);
    *(ushort4*)(Xb + (size_t)node * IN_F + lane * 4) = o;

    float ps[HEADS], pd[HEADS];
#pragma unroll
    for (int hd = 0; hd < HEADS; ++hd) {
        float4 s4 = *(const float4*)(va_s + hd * IN_F + lane * 4);
        float4 d4 = *(const float4*)(va_d + hd * IN_F + lane * 4);
        ps[hd] = v.x * s4.x + v.y * s4.y + v.z * s4.z + v.w * s4.w;
        pd[hd] = v.x * d4.x + v.y * d4.y + v.z * d4.z + v.w * d4.w;
    }
#pragma unroll
    for (int off = 32; off > 0; off >>= 1) {
#pragma unroll
        for (int hd = 0; hd < HEADS; ++hd) {
            ps[hd] += __shfl_xor(ps[hd], off, 64);
            pd[hd] += __shfl_xor(pd[hd], off, 64);
        }
    }
    if (lane == 0) {
        float4 s4 = make_float4(ps[0], ps[1], ps[2], ps[3]);
        float4 d4 = make_float4(pd[0], pd[1], pd[2], pd[3]);
        *(float4*)(a_s + node * 4) = s4;
        *(float4*)(a_d + node * 4) = d4;
    }
}

// --------- fused softmax + X-space aggregation: wave per node (proven 60.5 us) ---------
// LDS-DMA gathers with per-lane addresses (1 instr = 2 edge rows), 8-edge tiles
// double-buffered with counted vmcnt(4), packed f32x2 FMA, no barriers.
#define EDGE(E8)                                                            \
    {                                                                       \
        uint2 uu = *(const uint2*)(cons + (E8) * 512);                      \
        float4 wA = *(const float4*)(wp + (E8) * 8);                        \
        float4 wB = *(const float4*)(wp + (E8) * 8 + 4);                    \
        f32x2 f01 = {bflo(uu.x), bfhi(uu.x)};                               \
        f32x2 f23 = {bflo(uu.y), bfhi(uu.y)};                               \
        f32x2 w0p = {wA.x, wA.y}, w1p = {wA.z, wA.w};                       \
        f32x2 w2p = {wB.x, wB.y}, w3p = {wB.z, wB.w};                       \
        PKFMA(a01[0], f01, w0p); PKFMA(a23[0], f23, w0p);                   \
        PKFMA(a01[1], f01, w1p); PKFMA(a23[1], f23, w1p);                   \
        PKFMA(a01[2], f01, w2p); PKFMA(a23[2], f23, w2p);                   \
        PKFMA(a01[3], f01, w3p); PKFMA(a23[3], f23, w3p);                   \
    }

#define ISSUE(EB, DST)                                                      \
    {                                                                       \
        asm volatile("s_waitcnt lgkmcnt(0)" ::: "memory");                  \
        int s0_ = __shfl(sreg, (EB) + 0, 64);                               \
        int s1_ = __shfl(sreg, (EB) + 1, 64);                               \
        int s2_ = __shfl(sreg, (EB) + 2, 64);                               \
        int s3_ = __shfl(sreg, (EB) + 3, 64);                               \
        int s4_ = __shfl(sreg, (EB) + 4, 64);                               \
        int s5_ = __shfl(sreg, (EB) + 5, 64);                               \
        int s6_ = __shfl(sreg, (EB) + 6, 64);                               \
        int s7_ = __shfl(sreg, (EB) + 7, 64);                               \
        int sa_ = (lane & 32) ? s1_ : s0_;                                  \
        int sb_ = (lane & 32) ? s3_ : s2_;                                  \
        int sc_ = (lane & 32) ? s5_ : s4_;                                  \
        int sd_ = (lane & 32) ? s7_ : s6_;                                  \
        __builtin_amdgcn_global_load_lds((gp_t)(xb16 + (size_t)sa_ * 256),  \
                                         (lp_t)((DST) + 0 * 1024), 16, 0, 0);\
        __builtin_amdgcn_global_load_lds((gp_t)(xb16 + (size_t)sb_ * 256),  \
                                         (lp_t)((DST) + 1 * 1024), 16, 0, 0);\
        __builtin_amdgcn_global_load_lds((gp_t)(xb16 + (size_t)sc_ * 256),  \
                                         (lp_t)((DST) + 2 * 1024), 16, 0, 0);\
        __builtin_amdgcn_global_load_lds((gp_t)(xb16 + (size_t)sd_ * 256),  \
                                         (lp_t)((DST) + 3 * 1024), 16, 0, 0);\
    }

__global__ __launch_bounds__(256) void gat_agg(const ushort* __restrict__ Xb,
                                               const float* __restrict__ a_s,
                                               const float* __restrict__ a_d,
                                               const int* __restrict__ cursor,
                                               const int* __restrict__ table,
                                               ushort* __restrict__ Zb,
                                               int n_nodes) {
    __shared__ ushort xst[4][2][8][256];        // 4 waves x 2 bufs x 8 edges = 32 KB
    __shared__ float wse[4][CAP][8];            // {w,w} per head per edge     =  8 KB
    const int lane = threadIdx.x & 63;
    const int wid  = threadIdx.x >> 6;
    const int n = blockIdx.x * 4 + wid;
    if (n >= n_nodes) return;                   // no barriers in this kernel
    int deg = cursor[n]; if (deg > CAP) deg = CAP;
    const int* row = table + (size_t)n * CAP;
    const bool act = lane < deg;
    int sreg = act ? row[lane] : n;             // lane e holds src[e] (self if inactive)

    const ushort* xb16 = Xb + (lane & 31) * 8;  // per-lane 16B chunk base
    const uint2* xb2 = (const uint2*)Xb;
    uint2 uself = xb2[(size_t)n * 64 + lane];   // self row (registers)

    char* xb0 = (char*)&xst[wid][0][0][0];
    char* xb1 = (char*)&xst[wid][1][0][0];

    const int ntiles = (deg + 7) >> 3;
    if (ntiles > 0) ISSUE(0, xb0);              // tile 0 in flight under softmax

    // ---- softmax over self + in-edges (lane e owns edge e) ----
    const float4 ad4 = *(const float4*)(a_d + n * 4);
    const float4 as4 = *(const float4*)(a_s + n * 4);
    const float ad[4] = {ad4.x, ad4.y, ad4.z, ad4.w};
    float aself[4];
    {
        const float asn[4] = {as4.x, as4.y, as4.z, as4.w};
#pragma unroll
        for (int hd = 0; hd < 4; ++hd) {
            float al0 = asn[hd] + ad[hd];
            aself[hd] = al0 > 0.f ? al0 : NEG * al0;
        }
    }
    float al[4];
    {
        float4 av = *(const float4*)(a_s + (size_t)sreg * 4);
        const float as_[4] = {av.x, av.y, av.z, av.w};
#pragma unroll
        for (int hd = 0; hd < 4; ++hd) {
            float a = as_[hd] + ad[hd];
            a = a > 0.f ? a : NEG * a;
            al[hd] = act ? a : -1e30f;
        }
    }
    float m[4];
#pragma unroll
    for (int hd = 0; hd < 4; ++hd) m[hd] = al[hd];
#pragma unroll
    for (int off = 32; off > 0; off >>= 1)
#pragma unroll
        for (int hd = 0; hd < 4; ++hd)
            m[hd] = fmaxf(m[hd], __shfl_xor(m[hd], off, 64));
#pragma unroll
    for (int hd = 0; hd < 4; ++hd) m[hd] = fmaxf(m[hd], aself[hd]);

    float w[4], den[4];
#pragma unroll
    for (int hd = 0; hd < 4; ++hd) {
        w[hd] = act ? __expf(al[hd] - m[hd]) : 0.f;
        den[hd] = w[hd];
    }
#pragma unroll
    for (int off = 32; off > 0; off >>= 1)
#pragma unroll
        for (int hd = 0; hd < 4; ++hd)
            den[hd] += __shfl_xor(den[hd], off, 64);

    float es[4], rdv[4];
#pragma unroll
    for (int hd = 0; hd < 4; ++hd) {
        es[hd] = __expf(aself[hd] - m[hd]);
        rdv[hd] = 1.f / (den[hd] + es[hd]);
    }

    // publish duplicated weights {w,w} (wave-private; DS ops in-order per wave)
    *(float4*)&wse[wid][lane][0] = make_float4(w[0], w[0], w[1], w[1]);
    *(float4*)&wse[wid][lane][4] = make_float4(w[2], w[2], w[3], w[3]);

    // ---- aggregation: lane owns channels 4*lane..+3, all 4 heads, packed f32x2 ----
    f32x2 a01[4], a23[4];
    {
        f32x2 s01 = {bflo(uself.x), bfhi(uself.x)};
        f32x2 s23 = {bflo(uself.y), bfhi(uself.y)};
#pragma unroll
        for (int hd = 0; hd < 4; ++hd) {
            f32x2 eh = {es[hd], es[hd]};
            a01[hd] = s01 * eh;
            a23[hd] = s23 * eh;
        }
    }
#pragma unroll 1
    for (int t = 0; t < ntiles; ++t) {
        if (t + 1 < ntiles) {
            ISSUE((t + 1) * 8, ((t + 1) & 1) ? xb1 : xb0);
            asm volatile("s_waitcnt vmcnt(4)" ::: "memory");
        } else {
            asm volatile("s_waitcnt vmcnt(0)" ::: "memory");
        }
        const char* cons = ((t & 1) ? xb1 : xb0) + lane * 8;
        const float* wp = &wse[wid][t * 8][0];
        EDGE(0); EDGE(1); EDGE(2); EDGE(3);
        EDGE(4); EDGE(5); EDGE(6); EDGE(7);
    }

    ushort* zr = Zb + (size_t)n * K2;
#pragma unroll
    for (int hd = 0; hd < 4; ++hd) {
        f32x2 r2 = {rdv[hd], rdv[hd]};
        f32x2 z01 = a01[hd] * r2;
        f32x2 z23 = a23[hd] * r2;
        ushort4 z;
        z.x = f2bf(z01.x); z.y = f2bf(z01.y);
        z.z = f2bf(z23.x); z.w = f2bf(z23.y);
        *(ushort4*)(zr + hd * 256 + lane * 4) = z;
    }
}

// ---------------- out = tanh(0.25 * Zb @ WT2^T + bias), bf16 MFMA, K=1024 ----------------
// Proven LDS 2-phase pipeline (R9): tile 32x128, 938 blocks, LDS double-buffer,
// STAGE(t+1) before compute(t), counted vmcnt(5) + raw s_barrier. The b128
// LDS reads run at the structural 8-pass floor (bank-conflict counter is a
// red herring at this width); zero-LDS variant measured 3x slower (R11).
#define GBM 32
#define GBN 128
#define GBK 64

__global__ __launch_bounds__(256) void gemm2(const ushort* __restrict__ Zb,
                                             const ushort* __restrict__ WT2,
                                             const float* __restrict__ bias,
                                             float* __restrict__ out,
                                             int n_nodes) {
    __shared__ ushort As[2][GBM][GBK];          // 8 KB
    __shared__ ushort Bs[2][GBN][GBK];          // 32 KB
    const int tid = threadIdx.x;
    const int m0 = blockIdx.y * GBM;
    const int wave = tid >> 6, lane = tid & 63;
    const int wm = (wave & 1) * 16, wn = (wave >> 1) * 64;
    const int l15 = lane & 15, quad = lane >> 4;

    // staging: per instr a wave covers 8 rows (lane>>3), chunk slot lane&7.
    const int rr8 = lane >> 3;
    const int cg  = (lane & 7) ^ rr8;           // pre-swizzled global chunk
    const ushort* gA0 = Zb + (size_t)(m0 + wave * 8 + rr8) * K2 + cg * 8;
    const ushort* gB0 = WT2 + (size_t)(wave * 32 + rr8) * K2 + cg * 8;
    const ushort* gB1 = gB0 + 8 * K2;
    const ushort* gB2 = gB0 + 16 * K2;
    const ushort* gB3 = gB0 + 24 * K2;

#define STAGE(T, B)                                                          \
    {                                                                        \
        const int ko_ = (T) * GBK;                                           \
        __builtin_amdgcn_global_load_lds((gp_t)(gA0 + ko_),                  \
            (lp_t)&As[B][wave * 8][0], 16, 0, 0);                            \
        __builtin_amdgcn_global_load_lds((gp_t)(gB0 + ko_),                  \
            (lp_t)&Bs[B][wave * 32][0], 16, 0, 0);                           \
        __builtin_amdgcn_global_load_lds((gp_t)(gB1 + ko_),                  \
            (lp_t)&Bs[B][wave * 32 + 8][0], 16, 0, 0);                       \
        __builtin_amdgcn_global_load_lds((gp_t)(gB2 + ko_),                  \
            (lp_t)&Bs[B][wave * 32 + 16][0], 16, 0, 0);                      \
        __builtin_amdgcn_global_load_lds((gp_t)(gB3 + ko_),                  \
            (lp_t)&Bs[B][wave * 32 + 24][0], 16, 0, 0);                      \
    }

    f32x4 acc[4];
#pragma unroll
    for (int j = 0; j < 4; ++j) acc[j] = (f32x4){0.f, 0.f, 0.f, 0.f};

    const int NT = K2 / GBK;                    // 16
    STAGE(0, 0);
#pragma unroll 1
    for (int t = 0; t < NT; ++t) {
        const int b = t & 1;
        if (t + 1 < NT) {
            STAGE(t + 1, b ^ 1);
            asm volatile("s_waitcnt vmcnt(5)" ::: "memory");
        } else {
            asm volatile("s_waitcnt vmcnt(0)" ::: "memory");
        }
        asm volatile("s_barrier" ::: "memory");     // tile t visible to all waves

#pragma unroll
        for (int tt = 0; tt < 2; ++tt) {
            const int sl = ((tt * 4 + quad) ^ (l15 & 7)) * 8;
            short8 af = *(const short8*)&As[b][wm + l15][sl];
            short8 bf_[4];
#pragma unroll
            for (int fn = 0; fn < 4; ++fn)
                bf_[fn] = *(const short8*)&Bs[b][wn + fn * 16 + l15][sl];
#pragma unroll
            for (int fn = 0; fn < 4; ++fn)
                acc[fn] = __builtin_amdgcn_mfma_f32_16x16x32_bf16(
                    af, bf_[fn], acc[fn], 0, 0, 0);
        }
        asm volatile("s_barrier" ::: "memory");     // all reads done before overwrite
    }

    float bcol[4];
#pragma unroll
    for (int fn = 0; fn < 4; ++fn) bcol[fn] = bias[wn + fn * 16 + l15];

    int gmb = m0 + wm + quad * 4;
#pragma unroll
    for (int reg = 0; reg < 4; ++reg) {
        int gm = gmb + reg;
        if (gm < n_nodes) {
#pragma unroll
            for (int fn = 0; fn < 4; ++fn) {
                float o = tanhf(0.25f * acc[fn][reg] + bcol[fn]);
                out[(size_t)gm * OUT_F + wn + fn * 16 + l15] = o;
            }
        }
    }
}

extern "C" void kernel_launch(void* const* d_in, const int* in_sizes, int n_in,
                              void* d_out, int out_size, void* d_ws, size_t ws_size,
                              hipStream_t stream) {
    const float* x       = (const float*)d_in[0];
    const int*   ei      = (const int*)d_in[1];
    const float* W       = (const float*)d_in[2];
    const float* att_src = (const float*)d_in[3];
    const float* att_dst = (const float*)d_in[4];
    const float* bias    = (const float*)d_in[5];
    float* out = (float*)d_out;

    const int n_nodes = in_sizes[0] / IN_F;     // 30000
    const int n_edges = in_sizes[1] / 2;        // 480000
    const int* src = ei;
    const int* dst = ei + n_edges;

    char* ws = (char*)d_ws;
    size_t off = 0;
    auto alloc = [&](size_t bytes) -> void* {
        void* p = ws + off;
        off = (off + bytes + 255) & ~(size_t)255;
        return p;
    };
    ushort* Xb     = (ushort*)alloc((size_t)n_nodes * IN_F * sizeof(ushort));   // 15.4 MB
    ushort* Zb     = (ushort*)alloc((size_t)n_nodes * K2 * sizeof(ushort));     // 61.4 MB
    ushort* WT2    = (ushort*)alloc((size_t)OUT_F * K2 * sizeof(ushort));       // 0.26 MB (Zb tail pad)
    float*  va_s   = (float*)alloc((size_t)HEADS * IN_F * sizeof(float));
    float*  va_d   = (float*)alloc((size_t)HEADS * IN_F * sizeof(float));
    float*  a_s    = (float*)alloc((size_t)n_nodes * HEADS * sizeof(float));
    float*  a_d    = (float*)alloc((size_t)n_nodes * HEADS * sizeof(float));
    int*    cursor = (int*)alloc((size_t)n_nodes * sizeof(int));
    int*    table  = (int*)alloc((size_t)n_nodes * CAP * sizeof(int));          // 7.7 MB
    (void)ws_size; (void)n_in; (void)out_size;

    const int czb  = (n_nodes + 255) / 256;     // 118
    const int nebk = (n_edges + 255) / 256;     // 1875

    prep1<<<768 + czb, 256, 0, stream>>>(W, att_src, att_dst, WT2, va_s, va_d,
                                         cursor, n_nodes);
    prep2<<<nebk + (n_nodes + 3) / 4, 256, 0, stream>>>(x, va_s, va_d, src, dst,
                                                        Xb, a_s, a_d, cursor, table,
                                                        n_nodes, n_edges, nebk);
    gat_agg<<<(n_nodes + 3) / 4, 256, 0, stream>>>(Xb, a_s, a_d, cursor, table,
                                                   Zb, n_nodes);

    dim3 ggrid(1, (n_nodes + GBM - 1) / GBM);   // 1 x 938
    gemm2<<<ggrid, 256, 0, stream>>>(Zb, WT2, bias, out, n_nodes);
}

// Round 13
// 194.730 us; speedup vs baseline: 1.2717x; 1.0118x over previous
//
#include <hip/hip_runtime.h>
#include <math.h>

#define IN_F   256
#define OUT_F  128
#define HEADS  4
#define HD     (HEADS * OUT_F)   // 512
#define K2     1024              // stacked contraction: 4 heads x 256
#define NEG    0.2f
#define CAP    64                // per-node in-edge capacity (mean deg 16)

typedef __attribute__((ext_vector_type(8))) short short8;   // 8 bf16 = 4 VGPRs
typedef __attribute__((ext_vector_type(4))) float f32x4;
typedef __attribute__((ext_vector_type(2))) float f32x2;

typedef __attribute__((address_space(1))) const void* gp_t;
typedef __attribute__((address_space(3))) void* lp_t;

static __device__ __forceinline__ ushort f2bf(float f) {
    union { float f; unsigned u; } v; v.f = f;
    unsigned r = (v.u + 0x7FFFu + ((v.u >> 16) & 1u)) >> 16;   // RNE
    return (ushort)r;
}
static __device__ __forceinline__ float bflo(unsigned u) {
    union { unsigned u; float f; } v; v.u = u << 16; return v.f;
}
static __device__ __forceinline__ float bfhi(unsigned u) {
    union { unsigned u; float f; } v; v.u = u & 0xFFFF0000u; return v.f;
}

// packed fp32 FMA: D = A*B + D (per 32-bit half)
#define PKFMA(D, A, B) asm("v_pk_fma_f32 %0, %1, %2, %0" : "+v"(D) : "v"(A), "v"(B))

// ---------------- prep1: WT2 cvt + va + cursor zero (role by blockIdx) ----------------
__global__ __launch_bounds__(256) void prep1(const float* __restrict__ W,
                                             const float* __restrict__ att_src,
                                             const float* __restrict__ att_dst,
                                             ushort* __restrict__ WT2,
                                             float* __restrict__ va_s,
                                             float* __restrict__ va_d,
                                             int* __restrict__ cursor,
                                             int n_nodes) {
    const int b = blockIdx.x;
    const int tid = threadIdx.x;
    if (b < 512) {
        int idx = b * 256 + tid;               // 128*1024
        int cout = idx >> 10, kk = idx & 1023;
        int h = kk >> 8, c = kk & 255;
        WT2[idx] = f2bf(W[(size_t)c * HD + h * OUT_F + cout]);
    } else if (b < 768) {
        const int lane = tid & 63;
        const int p = (b - 512) * 4 + (tid >> 6);   // 0..1023 = h*256 + k
        const int h = p >> 8;
        const int k = p & 255;
        const float* wr = W + (size_t)k * HD + h * OUT_F;
        float w0 = wr[lane], w1 = wr[lane + 64];
        float s0 = att_src[h * OUT_F + lane], s1 = att_src[h * OUT_F + lane + 64];
        float d0 = att_dst[h * OUT_F + lane], d1 = att_dst[h * OUT_F + lane + 64];
        float ss = w0 * s0 + w1 * s1;
        float sd = w0 * d0 + w1 * d1;
#pragma unroll
        for (int off = 32; off > 0; off >>= 1) {
            ss += __shfl_xor(ss, off, 64);
            sd += __shfl_xor(sd, off, 64);
        }
        if (lane == 0) { va_s[p] = ss; va_d[p] = sd; }
    } else {
        int i = (b - 768) * 256 + tid;
        if (i < n_nodes) cursor[i] = 0;
    }
}

// ---------------- prep2: XCD-partitioned build_table + fused_x ----------------
// Edge blocks [0, ntb): swizzle class g = b & 7 lands on XCD g (round-robin
// heuristic; correctness does not depend on the mapping). Each class scans the
// FULL edge list (sequential int4, L3-served) but commits only dst in its
// range [g*nr, g*nr+nr) -> cursor atomics + table scatters become XCD-local
// (write working set 0.96 MB < 4 MB L2: lines accumulate all hits before one
// writeback; no cross-fabric atomic routing).
#define PROC(DD, SS)                                                        \
    if ((unsigned)((DD) - lo) < (unsigned)nr) {                             \
        int r_ = atomicAdd(&cursor[DD], 1);                                 \
        if (r_ < CAP) table[(size_t)(DD) * CAP + r_] = (SS);                \
    }

__global__ __launch_bounds__(256) void prep2(const float* __restrict__ X,
                                             const float* __restrict__ va_s,
                                             const float* __restrict__ va_d,
                                             const int* __restrict__ src,
                                             const int* __restrict__ dst,
                                             ushort* __restrict__ Xb,
                                             float* __restrict__ a_s,
                                             float* __restrict__ a_d,
                                             int* __restrict__ cursor,
                                             int* __restrict__ table,
                                             int n_nodes, int n_edges,
                                             int ntb, int nr) {
    const int b = blockIdx.x;
    const int tid = threadIdx.x;
    if (b < ntb) {
        const int g = b & 7;
        const int chunk = b >> 3;
        const int e0 = chunk * 1024 + tid * 4;
        const int lo = g * nr;
        if (e0 + 4 <= n_edges) {
            int4 s4 = *(const int4*)(src + e0);
            int4 d4 = *(const int4*)(dst + e0);
            PROC(d4.x, s4.x); PROC(d4.y, s4.y);
            PROC(d4.z, s4.z); PROC(d4.w, s4.w);
        } else if (e0 < n_edges) {
            for (int i = 0; e0 + i < n_edges; ++i) {
                int dd = dst[e0 + i], ss = src[e0 + i];
                PROC(dd, ss);
            }
        }
        return;
    }
    const int lane = tid & 63;
    const int node = (b - ntb) * 4 + (tid >> 6);
    if (node >= n_nodes) return;
    float4 v = *(const float4*)(X + (size_t)node * IN_F + lane * 4);
    ushort4 o; o.x = f2bf(v.x); o.y = f2bf(v.y); o.z = f2bf(v.z); o.w = f2bf(v.w);
    *(ushort4*)(Xb + (size_t)node * IN_F + lane * 4) = o;

    float ps[HEADS], pd[HEADS];
#pragma unroll
    for (int hd = 0; hd < HEADS; ++hd) {
        float4 s4 = *(const float4*)(va_s + hd * IN_F + lane * 4);
        float4 d4 = *(const float4*)(va_d + hd * IN_F + lane * 4);
        ps[hd] = v.x * s4.x + v.y * s4.y + v.z * s4.z + v.w * s4.w;
        pd[hd] = v.x * d4.x + v.y * d4.y + v.z * d4.z + v.w * d4.w;
    }
#pragma unroll
    for (int off = 32; off > 0; off >>= 1) {
#pragma unroll
        for (int hd = 0; hd < HEADS; ++hd) {
            ps[hd] += __shfl_xor(ps[hd], off, 64);
            pd[hd] += __shfl_xor(pd[hd], off, 64);
        }
    }
    if (lane == 0) {
        float4 s4 = make_float4(ps[0], ps[1], ps[2], ps[3]);
        float4 d4 = make_float4(pd[0], pd[1], pd[2], pd[3]);
        *(float4*)(a_s + node * 4) = s4;
        *(float4*)(a_d + node * 4) = d4;
    }
}

// --------- fused softmax + X-space aggregation: wave per node (proven 60.5 us) ---------
// LDS-DMA gathers with per-lane addresses (1 instr = 2 edge rows), 8-edge tiles
// double-buffered with counted vmcnt(4), packed f32x2 FMA, no barriers.
#define EDGE(E8)                                                            \
    {                                                                       \
        uint2 uu = *(const uint2*)(cons + (E8) * 512);                      \
        float4 wA = *(const float4*)(wp + (E8) * 8);                        \
        float4 wB = *(const float4*)(wp + (E8) * 8 + 4);                    \
        f32x2 f01 = {bflo(uu.x), bfhi(uu.x)};                               \
        f32x2 f23 = {bflo(uu.y), bfhi(uu.y)};                               \
        f32x2 w0p = {wA.x, wA.y}, w1p = {wA.z, wA.w};                       \
        f32x2 w2p = {wB.x, wB.y}, w3p = {wB.z, wB.w};                       \
        PKFMA(a01[0], f01, w0p); PKFMA(a23[0], f23, w0p);                   \
        PKFMA(a01[1], f01, w1p); PKFMA(a23[1], f23, w1p);                   \
        PKFMA(a01[2], f01, w2p); PKFMA(a23[2], f23, w2p);                   \
        PKFMA(a01[3], f01, w3p); PKFMA(a23[3], f23, w3p);                   \
    }

#define ISSUE(EB, DST)                                                      \
    {                                                                       \
        asm volatile("s_waitcnt lgkmcnt(0)" ::: "memory");                  \
        int s0_ = __shfl(sreg, (EB) + 0, 64);                               \
        int s1_ = __shfl(sreg, (EB) + 1, 64);                               \
        int s2_ = __shfl(sreg, (EB) + 2, 64);                               \
        int s3_ = __shfl(sreg, (EB) + 3, 64);                               \
        int s4_ = __shfl(sreg, (EB) + 4, 64);                               \
        int s5_ = __shfl(sreg, (EB) + 5, 64);                               \
        int s6_ = __shfl(sreg, (EB) + 6, 64);                               \
        int s7_ = __shfl(sreg, (EB) + 7, 64);                               \
        int sa_ = (lane & 32) ? s1_ : s0_;                                  \
        int sb_ = (lane & 32) ? s3_ : s2_;                                  \
        int sc_ = (lane & 32) ? s5_ : s4_;                                  \
        int sd_ = (lane & 32) ? s7_ : s6_;                                  \
        __builtin_amdgcn_global_load_lds((gp_t)(xb16 + (size_t)sa_ * 256),  \
                                         (lp_t)((DST) + 0 * 1024), 16, 0, 0);\
        __builtin_amdgcn_global_load_lds((gp_t)(xb16 + (size_t)sb_ * 256),  \
                                         (lp_t)((DST) + 1 * 1024), 16, 0, 0);\
        __builtin_amdgcn_global_load_lds((gp_t)(xb16 + (size_t)sc_ * 256),  \
                                         (lp_t)((DST) + 2 * 1024), 16, 0, 0);\
        __builtin_amdgcn_global_load_lds((gp_t)(xb16 + (size_t)sd_ * 256),  \
                                         (lp_t)((DST) + 3 * 1024), 16, 0, 0);\
    }

__global__ __launch_bounds__(256) void gat_agg(const ushort* __restrict__ Xb,
                                               const float* __restrict__ a_s,
                                               const float* __restrict__ a_d,
                                               const int* __restrict__ cursor,
                                               const int* __restrict__ table,
                                               ushort* __restrict__ Zb,
                                               int n_nodes) {
    __shared__ ushort xst[4][2][8][256];        // 4 waves x 2 bufs x 8 edges = 32 KB
    __shared__ float wse[4][CAP][8];            // {w,w} per head per edge     =  8 KB
    const int lane = threadIdx.x & 63;
    const int wid  = threadIdx.x >> 6;
    const int n = blockIdx.x * 4 + wid;
    if (n >= n_nodes) return;                   // no barriers in this kernel
    int deg = cursor[n]; if (deg > CAP) deg = CAP;
    const int* row = table + (size_t)n * CAP;
    const bool act = lane < deg;
    int sreg = act ? row[lane] : n;             // lane e holds src[e] (self if inactive)

    const ushort* xb16 = Xb + (lane & 31) * 8;  // per-lane 16B chunk base
    const uint2* xb2 = (const uint2*)Xb;
    uint2 uself = xb2[(size_t)n * 64 + lane];   // self row (registers)

    char* xb0 = (char*)&xst[wid][0][0][0];
    char* xb1 = (char*)&xst[wid][1][0][0];

    const int ntiles = (deg + 7) >> 3;
    if (ntiles > 0) ISSUE(0, xb0);              // tile 0 in flight under softmax

    // ---- softmax over self + in-edges (lane e owns edge e) ----
    const float4 ad4 = *(const float4*)(a_d + n * 4);
    const float4 as4 = *(const float4*)(a_s + n * 4);
    const float ad[4] = {ad4.x, ad4.y, ad4.z, ad4.w};
    float aself[4];
    {
        const float asn[4] = {as4.x, as4.y, as4.z, as4.w};
#pragma unroll
        for (int hd = 0; hd < 4; ++hd) {
            float al0 = asn[hd] + ad[hd];
            aself[hd] = al0 > 0.f ? al0 : NEG * al0;
        }
    }
    float al[4];
    {
        float4 av = *(const float4*)(a_s + (size_t)sreg * 4);
        const float as_[4] = {av.x, av.y, av.z, av.w};
#pragma unroll
        for (int hd = 0; hd < 4; ++hd) {
            float a = as_[hd] + ad[hd];
            a = a > 0.f ? a : NEG * a;
            al[hd] = act ? a : -1e30f;
        }
    }
    float m[4];
#pragma unroll
    for (int hd = 0; hd < 4; ++hd) m[hd] = al[hd];
#pragma unroll
    for (int off = 32; off > 0; off >>= 1)
#pragma unroll
        for (int hd = 0; hd < 4; ++hd)
            m[hd] = fmaxf(m[hd], __shfl_xor(m[hd], off, 64));
#pragma unroll
    for (int hd = 0; hd < 4; ++hd) m[hd] = fmaxf(m[hd], aself[hd]);

    float w[4], den[4];
#pragma unroll
    for (int hd = 0; hd < 4; ++hd) {
        w[hd] = act ? __expf(al[hd] - m[hd]) : 0.f;
        den[hd] = w[hd];
    }
#pragma unroll
    for (int off = 32; off > 0; off >>= 1)
#pragma unroll
        for (int hd = 0; hd < 4; ++hd)
            den[hd] += __shfl_xor(den[hd], off, 64);

    float es[4], rdv[4];
#pragma unroll
    for (int hd = 0; hd < 4; ++hd) {
        es[hd] = __expf(aself[hd] - m[hd]);
        rdv[hd] = 1.f / (den[hd] + es[hd]);
    }

    // publish duplicated weights {w,w} (wave-private; DS ops in-order per wave)
    *(float4*)&wse[wid][lane][0] = make_float4(w[0], w[0], w[1], w[1]);
    *(float4*)&wse[wid][lane][4] = make_float4(w[2], w[2], w[3], w[3]);

    // ---- aggregation: lane owns channels 4*lane..+3, all 4 heads, packed f32x2 ----
    f32x2 a01[4], a23[4];
    {
        f32x2 s01 = {bflo(uself.x), bfhi(uself.x)};
        f32x2 s23 = {bflo(uself.y), bfhi(uself.y)};
#pragma unroll
        for (int hd = 0; hd < 4; ++hd) {
            f32x2 eh = {es[hd], es[hd]};
            a01[hd] = s01 * eh;
            a23[hd] = s23 * eh;
        }
    }
#pragma unroll 1
    for (int t = 0; t < ntiles; ++t) {
        if (t + 1 < ntiles) {
            ISSUE((t + 1) * 8, ((t + 1) & 1) ? xb1 : xb0);
            asm volatile("s_waitcnt vmcnt(4)" ::: "memory");
        } else {
            asm volatile("s_waitcnt vmcnt(0)" ::: "memory");
        }
        const char* cons = ((t & 1) ? xb1 : xb0) + lane * 8;
        const float* wp = &wse[wid][t * 8][0];
        EDGE(0); EDGE(1); EDGE(2); EDGE(3);
        EDGE(4); EDGE(5); EDGE(6); EDGE(7);
    }

    ushort* zr = Zb + (size_t)n * K2;
#pragma unroll
    for (int hd = 0; hd < 4; ++hd) {
        f32x2 r2 = {rdv[hd], rdv[hd]};
        f32x2 z01 = a01[hd] * r2;
        f32x2 z23 = a23[hd] * r2;
        ushort4 z;
        z.x = f2bf(z01.x); z.y = f2bf(z01.y);
        z.z = f2bf(z23.x); z.w = f2bf(z23.y);
        *(ushort4*)(zr + hd * 256 + lane * 4) = z;
    }
}

// ---------------- out = tanh(0.25 * Zb @ WT2^T + bias), bf16 MFMA, K=1024 ----------------
// Proven LDS 2-phase pipeline: tile 32x128, 938 blocks, LDS double-buffer,
// STAGE(t+1) before compute(t), counted vmcnt(5) + raw s_barrier.
#define GBM 32
#define GBN 128
#define GBK 64

__global__ __launch_bounds__(256) void gemm2(const ushort* __restrict__ Zb,
                                             const ushort* __restrict__ WT2,
                                             const float* __restrict__ bias,
                                             float* __restrict__ out,
                                             int n_nodes) {
    __shared__ ushort As[2][GBM][GBK];          // 8 KB
    __shared__ ushort Bs[2][GBN][GBK];          // 32 KB
    const int tid = threadIdx.x;
    const int m0 = blockIdx.y * GBM;
    const int wave = tid >> 6, lane = tid & 63;
    const int wm = (wave & 1) * 16, wn = (wave >> 1) * 64;
    const int l15 = lane & 15, quad = lane >> 4;

    // staging: per instr a wave covers 8 rows (lane>>3), chunk slot lane&7.
    const int rr8 = lane >> 3;
    const int cg  = (lane & 7) ^ rr8;           // pre-swizzled global chunk
    const ushort* gA0 = Zb + (size_t)(m0 + wave * 8 + rr8) * K2 + cg * 8;
    const ushort* gB0 = WT2 + (size_t)(wave * 32 + rr8) * K2 + cg * 8;
    const ushort* gB1 = gB0 + 8 * K2;
    const ushort* gB2 = gB0 + 16 * K2;
    const ushort* gB3 = gB0 + 24 * K2;

#define STAGE(T, B)                                                          \
    {                                                                        \
        const int ko_ = (T) * GBK;                                           \
        __builtin_amdgcn_global_load_lds((gp_t)(gA0 + ko_),                  \
            (lp_t)&As[B][wave * 8][0], 16, 0, 0);                            \
        __builtin_amdgcn_global_load_lds((gp_t)(gB0 + ko_),                  \
            (lp_t)&Bs[B][wave * 32][0], 16, 0, 0);                           \
        __builtin_amdgcn_global_load_lds((gp_t)(gB1 + ko_),                  \
            (lp_t)&Bs[B][wave * 32 + 8][0], 16, 0, 0);                       \
        __builtin_amdgcn_global_load_lds((gp_t)(gB2 + ko_),                  \
            (lp_t)&Bs[B][wave * 32 + 16][0], 16, 0, 0);                      \
        __builtin_amdgcn_global_load_lds((gp_t)(gB3 + ko_),                  \
            (lp_t)&Bs[B][wave * 32 + 24][0], 16, 0, 0);                      \
    }

    f32x4 acc[4];
#pragma unroll
    for (int j = 0; j < 4; ++j) acc[j] = (f32x4){0.f, 0.f, 0.f, 0.f};

    const int NT = K2 / GBK;                    // 16
    STAGE(0, 0);
#pragma unroll 1
    for (int t = 0; t < NT; ++t) {
        const int b = t & 1;
        if (t + 1 < NT) {
            STAGE(t + 1, b ^ 1);
            asm volatile("s_waitcnt vmcnt(5)" ::: "memory");
        } else {
            asm volatile("s_waitcnt vmcnt(0)" ::: "memory");
        }
        asm volatile("s_barrier" ::: "memory");     // tile t visible to all waves

#pragma unroll
        for (int tt = 0; tt < 2; ++tt) {
            const int sl = ((tt * 4 + quad) ^ (l15 & 7)) * 8;
            short8 af = *(const short8*)&As[b][wm + l15][sl];
            short8 bf_[4];
#pragma unroll
            for (int fn = 0; fn < 4; ++fn)
                bf_[fn] = *(const short8*)&Bs[b][wn + fn * 16 + l15][sl];
#pragma unroll
            for (int fn = 0; fn < 4; ++fn)
                acc[fn] = __builtin_amdgcn_mfma_f32_16x16x32_bf16(
                    af, bf_[fn], acc[fn], 0, 0, 0);
        }
        asm volatile("s_barrier" ::: "memory");     // all reads done before overwrite
    }

    float bcol[4];
#pragma unroll
    for (int fn = 0; fn < 4; ++fn) bcol[fn] = bias[wn + fn * 16 + l15];

    int gmb = m0 + wm + quad * 4;
#pragma unroll
    for (int reg = 0; reg < 4; ++reg) {
        int gm = gmb + reg;
        if (gm < n_nodes) {
#pragma unroll
            for (int fn = 0; fn < 4; ++fn) {
                float o = tanhf(0.25f * acc[fn][reg] + bcol[fn]);
                out[(size_t)gm * OUT_F + wn + fn * 16 + l15] = o;
            }
        }
    }
}

extern "C" void kernel_launch(void* const* d_in, const int* in_sizes, int n_in,
                              void* d_out, int out_size, void* d_ws, size_t ws_size,
                              hipStream_t stream) {
    const float* x       = (const float*)d_in[0];
    const int*   ei      = (const int*)d_in[1];
    const float* W       = (const float*)d_in[2];
    const float* att_src = (const float*)d_in[3];
    const float* att_dst = (const float*)d_in[4];
    const float* bias    = (const float*)d_in[5];
    float* out = (float*)d_out;

    const int n_nodes = in_sizes[0] / IN_F;     // 30000
    const int n_edges = in_sizes[1] / 2;        // 480000
    const int* src = ei;
    const int* dst = ei + n_edges;

    char* ws = (char*)d_ws;
    size_t off = 0;
    auto alloc = [&](size_t bytes) -> void* {
        void* p = ws + off;
        off = (off + bytes + 255) & ~(size_t)255;
        return p;
    };
    ushort* Xb     = (ushort*)alloc((size_t)n_nodes * IN_F * sizeof(ushort));   // 15.4 MB
    ushort* Zb     = (ushort*)alloc((size_t)n_nodes * K2 * sizeof(ushort));     // 61.4 MB
    ushort* WT2    = (ushort*)alloc((size_t)OUT_F * K2 * sizeof(ushort));       // 0.26 MB (Zb tail pad)
    float*  va_s   = (float*)alloc((size_t)HEADS * IN_F * sizeof(float));
    float*  va_d   = (float*)alloc((size_t)HEADS * IN_F * sizeof(float));
    float*  a_s    = (float*)alloc((size_t)n_nodes * HEADS * sizeof(float));
    float*  a_d    = (float*)alloc((size_t)n_nodes * HEADS * sizeof(float));
    int*    cursor = (int*)alloc((size_t)n_nodes * sizeof(int));
    int*    table  = (int*)alloc((size_t)n_nodes * CAP * sizeof(int));          // 7.7 MB
    (void)ws_size; (void)n_in; (void)out_size;

    const int czb  = (n_nodes + 255) / 256;     // 118
    const int nech = (n_edges + 1023) / 1024;   // 469 edge chunks (4 edges/thread)
    const int ntb  = nech * 8;                  // x8 swizzle classes = 3752 blocks
    const int nr   = (n_nodes + 7) / 8;         // 3750 dst-range per class

    prep1<<<768 + czb, 256, 0, stream>>>(W, att_src, att_dst, WT2, va_s, va_d,
                                         cursor, n_nodes);
    prep2<<<ntb + (n_nodes + 3) / 4, 256, 0, stream>>>(x, va_s, va_d, src, dst,
                                                       Xb, a_s, a_d, cursor, table,
                                                       n_nodes, n_edges, ntb, nr);
    gat_agg<<<(n_nodes + 3) / 4, 256, 0, stream>>>(Xb, a_s, a_d, cursor, table,
                                                   Zb, n_nodes);

    dim3 ggrid(1, (n_nodes + GBM - 1) / GBM);   // 1 x 938
    gemm2<<<ggrid, 256, 0, stream>>>(Zb, WT2, bias, out, n_nodes);
}